// Round 2
// baseline (662.816 us; speedup 1.0000x reference)
//
#include <hip/hip_runtime.h>
#include <stdint.h>

typedef __bf16 bf16_t;
typedef __bf16 bf16x8 __attribute__((ext_vector_type(8)));
typedef __bf16 bf16x4 __attribute__((ext_vector_type(4)));
typedef float f32x4 __attribute__((ext_vector_type(4)));

// Async global->LDS, 16B per lane (wave-uniform base + lane*16).
#define GLOAD16(gp, lp)                                                        \
    __builtin_amdgcn_global_load_lds(                                          \
        (const __attribute__((address_space(1))) void*)(gp),                   \
        (__attribute__((address_space(3))) void*)(lp), 16, 0, 0)

#define MFMA16(a, b, c) __builtin_amdgcn_mfma_f32_16x16x32_bf16(a, b, c, 0, 0, 0)

#define SB() __builtin_amdgcn_sched_barrier(0)
#define BAR() asm volatile("s_barrier" ::: "memory")
#define LGKM0() asm volatile("s_waitcnt lgkmcnt(0)" ::: "memory")
#define VMW(n) asm volatile("s_waitcnt vmcnt(" #n ")" ::: "memory")

// One phase: [gate][stage] | barrier | lgkm(0) | prefetch(next) | MFMA | barrier
// Prefetch-under-MFMA: phase p issues phase p+1's ds_reads inside p's MFMA
// region, so LDS traffic runs while the MFMA pipe is busy and the next
// phase's lgkmcnt(0) is ~free. vmcnt gates sit BEFORE the barrier so that
// after the barrier ALL waves' staging loads (per-wave counters!) are
// retired before any wave prefetches the gated region.
#define PHASE(GATE, STAGE, PF, MM)                                             \
    do {                                                                       \
        GATE;                                                                  \
        STAGE;                                                                 \
        SB();                                                                  \
        BAR();                                                                 \
        LGKM0();                                                               \
        SB();                                                                  \
        __builtin_amdgcn_s_setprio(1);                                         \
        PF;                                                                    \
        SB();                                                                  \
        MM;                                                                    \
        __builtin_amdgcn_s_setprio(0);                                         \
        SB();                                                                  \
        BAR();                                                                 \
    } while (0)

// 16-MFMA cluster: one C-quadrant (4 m-frags x 2 n-frags) x K=64 (2 halves).
#define MMCL(aa, bb, mo, no)                                                   \
    do {                                                                       \
        _Pragma("unroll") for (int m_ = 0; m_ < 4; ++m_) {                     \
            _Pragma("unroll") for (int n_ = 0; n_ < 2; ++n_) {                 \
                acc[mo + m_][no + n_] =                                        \
                    MFMA16(aa[m_][0], bb[n_][0], acc[mo + m_][no + n_]);       \
                acc[mo + m_][no + n_] =                                        \
                    MFMA16(aa[m_][1], bb[n_][1], acc[mo + m_][no + n_]);       \
            }                                                                  \
        }                                                                      \
    } while (0)

// Fragment prefetch from LDS (ro: first m-frag row-group; no: first n-frag).
#define PFA(dst, base, ro)                                                     \
    do {                                                                       \
        _Pragma("unroll") for (int m_ = 0; m_ < 4; ++m_) {                     \
            dst[m_][0] = *(const bf16x8*)((base) + offA0 + (ro + m_) * 1024);  \
            dst[m_][1] = *(const bf16x8*)((base) + offA1 + (ro + m_) * 1024);  \
        }                                                                      \
    } while (0)
#define PFB(dst, base, no)                                                     \
    do {                                                                       \
        _Pragma("unroll") for (int n_ = 0; n_ < 2; ++n_) {                     \
            dst[n_][0] = *(const bf16x8*)((base) + offB0 + (no + n_) * 1024);  \
            dst[n_][1] = *(const bf16x8*)((base) + offB1 + (no + n_) * 1024);  \
        }                                                                      \
    } while (0)

// BK=64 LDS tiles: row = 64 bf16 = 128 B = 32 banks; chunk c of row r lives
// in slot c ^ (r&7) (pre-swizzled global source, linear LDS dest). Readers
// XOR the same way -> 2-way (free) on ds_read_b128.

// ---------------------------------------------------------------------------
// All fp32 -> bf16 conversions in ONE launch (7 segments).  (unchanged)
// ---------------------------------------------------------------------------
__global__ __launch_bounds__(256) void cvt_all_kernel(
    const float* __restrict__ x, const float* __restrict__ Wgu,
    const float* __restrict__ Bgu, const float* __restrict__ Wd,
    const float* __restrict__ Bd, const float* __restrict__ Agu,
    const float* __restrict__ Ad, bf16_t* __restrict__ X1,
    bf16_t* __restrict__ W1, bf16_t* __restrict__ W2,
    bf16_t* __restrict__ Abf, bf16_t* __restrict__ Adbf) {
    int b = blockIdx.x;
    const float* src;
    bf16_t* dst;
    int cshift, cmask, ldd, coff, lb;
    if (b < 16384) {
        src = x; dst = X1; cshift = 11; cmask = 2047; ldd = 2112; coff = 0; lb = b;
    } else if (b < 32768) {
        src = Wgu; dst = W1; cshift = 11; cmask = 2047; ldd = 2112; coff = 0; lb = b - 16384;
    } else if (b < 33280) {
        src = Bgu; dst = W1; cshift = 6; cmask = 63; ldd = 2112; coff = 2048; lb = b - 32768;
    } else if (b < 41472) {
        src = Wd; dst = W2; cshift = 12; cmask = 4095; ldd = 4160; coff = 0; lb = b - 33280;
    } else if (b < 41600) {
        src = Bd; dst = W2; cshift = 6; cmask = 63; ldd = 4160; coff = 4096; lb = b - 41472;
    } else if (b < 41728) {
        src = Agu; dst = Abf; cshift = 11; cmask = 2047; ldd = 2048; coff = 0; lb = b - 41600;
    } else {
        src = Ad; dst = Adbf; cshift = 12; cmask = 4095; ldd = 4096; coff = 0; lb = b - 41728;
    }
    int idx = (lb * 256 + threadIdx.x) << 2;
    int r = idx >> cshift;
    int c = idx & cmask;
    float4 v = *(const float4*)(src + idx);
    bf16x4 o = {(bf16_t)v.x, (bf16_t)v.y, (bf16_t)v.z, (bf16_t)v.w};
    *(bf16x4*)(dst + (size_t)r * ldd + coff + c) = o;
}

// ---------------------------------------------------------------------------
// LoRA GEMM (unchanged): t = 0.25 * (A[M x K] @ Bw[64 x K]^T) -> dst cols.
// ---------------------------------------------------------------------------
__global__ __launch_bounds__(256) void lora_kernel(const bf16_t* __restrict__ A,
                                                   int lda,
                                                   const bf16_t* __restrict__ Bw,
                                                   int K, bf16_t* __restrict__ dst,
                                                   int ldd, int coff) {
    __shared__ __align__(16) bf16_t As[64 * 64];
    __shared__ __align__(16) bf16_t Bs[64 * 64];
    const int t = threadIdx.x;
    const int m0 = blockIdx.x * 64;
    const int lane = t & 63, w = t >> 6;
    const int ln15 = lane & 15, q = lane >> 4;

    const int lrow = t >> 3;
    const int lchunk = (t & 7) ^ (lrow & 7);
    const bf16_t* gaL = A + (size_t)(m0 + lrow) * lda + lchunk * 8;
    const bf16_t* gbL = Bw + (size_t)lrow * K + lchunk * 8;
    bf16_t* lA = As + t * 8;
    bf16_t* lB = Bs + t * 8;

    const f32x4 z = {0.f, 0.f, 0.f, 0.f};
    f32x4 acc[4];
#pragma unroll
    for (int j = 0; j < 4; ++j) acc[j] = z;

    int aoffs[2], boffs[2][4];
#pragma unroll
    for (int s = 0; s < 2; ++s) {
        int rowa = w * 16 + ln15;
        aoffs[s] = rowa * 64 + (((q + 4 * s) ^ (rowa & 7)) << 3);
#pragma unroll
        for (int j = 0; j < 4; ++j) {
            int rowb = j * 16 + ln15;
            boffs[s][j] = rowb * 64 + (((q + 4 * s) ^ (rowb & 7)) << 3);
        }
    }

    for (int kt = 0; kt < K; kt += 64) {
        GLOAD16(gaL, lA);
        GLOAD16(gaL + (size_t)32 * lda, lA + 32 * 64);
        GLOAD16(gbL, lB);
        GLOAD16(gbL + (size_t)32 * K, lB + 32 * 64);
        __syncthreads();
#pragma unroll
        for (int s = 0; s < 2; ++s) {
            bf16x8 av = *(const bf16x8*)(As + aoffs[s]);
#pragma unroll
            for (int j = 0; j < 4; ++j) {
                bf16x8 bv = *(const bf16x8*)(Bs + boffs[s][j]);
                acc[j] = MFMA16(av, bv, acc[j]);
            }
        }
        __syncthreads();
        gaL += 64;
        gbL += 64;
    }

#pragma unroll
    for (int j = 0; j < 4; ++j)
#pragma unroll
        for (int rg = 0; rg < 4; ++rg) {
            int m = m0 + w * 16 + q * 4 + rg;
            dst[(size_t)m * ldd + coff + j * 16 + ln15] = (bf16_t)(acc[j][rg] * 0.25f);
        }
}

// ---------------------------------------------------------------------------
// 256x256 8-phase GEMM core with prefetch-under-MFMA.
// 512 thr = 8 waves (2M x 4N), per-wave 128x64 out. LDS 128 KiB (2 buffers).
// 2 tiles per loop iter (even->buf0, odd->buf1); b0 frags reg-double-buffered
// (b0e/b0o) so every array index is compile-time (no scratch).
// Stage schedule (unit = 2 GLOADs): p1:A1(o) p2:A0(e+2) p3:Blo(e+2)
// p4:Bhi(e+2) p5:A1(e+2) p6:A0(g+3) p7:Blo(g+3) p8:Bhi(g+3).
// Prefetch (for NEXT phase's MFMA): p1:b1(e) p2:a1(e) p3:b0o(o) p4:a0(o)
// p5:b1(o) p6:a1(o) p7:b0e(e+2) p8:a0(e+2).  Balanced 4/8 reads per phase.
// vmcnt gates (derived; before the barrier guarding the prefetch):
//   p3: vmcnt(4)  -> Blo/Bhi(o) resident        (retires through Bhi(o))
//   p6: vmcnt(8)  -> A1(o) resident             (retires through A1(o))
//   p7: vmcnt(2)  -> Blo/Bhi(e+2) resident      (also covers tail pair)
// A1(e) residency for p2's prefetch is guaranteed by the PREVIOUS pair's
// p7 vmcnt(2) (prologue for the first pair). Never drains to 0 in-loop.
// Every stage targets a region whose last ds_read completed >= 1 barrier
// earlier (verified per-region; see per-phase comments).
// ---------------------------------------------------------------------------
template <int LDA_, int LDB_, int NT_>
__device__ __forceinline__ void gemm8p_core(const bf16_t* __restrict__ gA,
                                            const bf16_t* __restrict__ gB0,
                                            const bf16_t* __restrict__ gB2,
                                            bf16_t* smem, const int t,
                                            const int offA0, const int offA1,
                                            const int offB0, const int offB1,
                                            f32x4 (&acc)[8][4]) {
    static_assert(NT_ & 1, "NT_ must be odd (pairs + tail tile)");
    bf16_t* const As0 = smem;
    bf16_t* const As1 = smem + 16384;
    bf16_t* const Bs0 = smem + 32768;
    bf16_t* const Bs1 = smem + 49152;

    auto stgA0 = [&](int kt, bf16_t* d) {  // rows {0-63,128-191}
        GLOAD16(gA + kt, d + t * 8);
        GLOAD16(gA + (size_t)128 * LDA_ + kt, d + 128 * 64 + t * 8);
    };
    auto stgA1 = [&](int kt, bf16_t* d) {  // rows {64-127,192-255}
        GLOAD16(gA + (size_t)64 * LDA_ + kt, d + 64 * 64 + t * 8);
        GLOAD16(gA + (size_t)192 * LDA_ + kt, d + 192 * 64 + t * 8);
    };
    auto stgBlo = [&](int kt, bf16_t* d) {  // B rows 0-127
        GLOAD16(gB0 + kt, d + t * 8);
        GLOAD16(gB0 + (size_t)64 * LDB_ + kt, d + 64 * 64 + t * 8);
    };
    auto stgBhi = [&](int kt, bf16_t* d) {  // B rows 128-255
        GLOAD16(gB2 + kt, d + 128 * 64 + t * 8);
        GLOAD16(gB2 + (size_t)64 * LDB_ + kt, d + 192 * 64 + t * 8);
    };

    bf16x8 a0[4][2], a1[4][2], b0e[2][2], b0o[2][2], b1v[2][2];

    // prologue: tile0 full (8 loads) -> buf0, tile1 minus A1 (6) -> buf1.
    stgA0(0, As0);
    stgA1(0, As0);
    stgBlo(0, Bs0);
    stgBhi(0, Bs0);
    stgA0(64, As1);
    stgBlo(64, Bs1);
    stgBhi(64, Bs1);
    VMW(6);  // tile0 resident (leaves tile1's 6 in flight)
    BAR();
    PFA(a0, As0, 0);       // a0(0)
    PFB(b0e, Bs0, 0);      // b0(0)

    for (int g = 0; g + 2 < NT_; g += 2) {
        const int k1 = (g + 1) << 6, k2 = (g + 2) << 6, k3 = (g + 3) << 6;
        const bool s3 = (g + 3 < NT_);

        // p1(e): stage A1(o)->buf1 (A1 of buf1 last read @p6 prev pair)
        PHASE((void)0, stgA1(k1, As1), PFB(b1v, Bs0, 2), MMCL(a0, b0e, 0, 0));
        // p2(e): stage A0(e+2)->buf0 (A0 buf0 last read @p8 prev / prologue)
        PHASE((void)0, stgA0(k2, As0), PFA(a1, As0, 4), MMCL(a0, b1v, 0, 2));
        // p3(e): gate B(o) resident; stage Blo(e+2) (Blo buf0 last read @p1)
        PHASE(VMW(4), stgBlo(k2, Bs0), PFB(b0o, Bs1, 0), MMCL(a1, b1v, 4, 2));
        // p4(e): stage Bhi(e+2) (Bhi buf0 last read @p1); A0(o) ok via p3 gate
        PHASE((void)0, stgBhi(k2, Bs0), PFA(a0, As1, 0), MMCL(a1, b0e, 4, 0));
        // p5(o): stage A1(e+2)->buf0 (A1 buf0 last read @p2)
        PHASE((void)0, stgA1(k2, As0), PFB(b1v, Bs1, 2), MMCL(a0, b0o, 0, 0));
        // p6(o): gate A1(o); stage A0(g+3)->buf1 (A0 buf1 last read @p4)
        PHASE(VMW(8), if (s3) stgA0(k3, As1), PFA(a1, As1, 4),
              MMCL(a0, b1v, 0, 2));
        // p7(o): gate B(e+2); stage Blo(g+3) (Blo buf1 last read @p5)
        PHASE(VMW(2), if (s3) stgBlo(k3, Bs1), PFB(b0e, Bs0, 0),
              MMCL(a1, b1v, 4, 2));
        // p8(o): stage Bhi(g+3) (Bhi buf1 last read @p5); A0(e+2) ok via p7
        PHASE((void)0, if (s3) stgBhi(k3, Bs1), PFA(a0, As0, 0),
              MMCL(a1, b0o, 4, 0));
    }

    // tail tile T = NT_-1 (even parity, buf0); a0/b0e already prefetched.
    PHASE((void)0, (void)0, PFB(b1v, Bs0, 2), MMCL(a0, b0e, 0, 0));
    PHASE(VMW(0), (void)0, PFA(a1, As0, 4), MMCL(a0, b1v, 0, 2));
    PHASE((void)0, (void)0, (void)0, MMCL(a1, b1v, 4, 2));
    PHASE((void)0, (void)0, (void)0, MMCL(a1, b0e, 4, 0));
}

// Epilogue LDS park swizzle: 2-way max (free). bit4 from row-bit2 (q&1),
// bits2-3 from row bits 3-4 -> the 4 q-groups of a store split across
// bank-halves instead of stacking 4-deep on one bank.
__device__ __forceinline__ int eswz(int row, int col) {
    return col ^ (((row >> 2) & 1) << 4) ^ (((row >> 3) & 3) << 2);
}

// ---------------------------------------------------------------------------
// GEMM1 (fused gate_up + SwiGLU): X1[8192x2112] @ [gate|up]^T.
// B rows 0-127 = gate cols n0.., rows 128-255 = up (W rows 4096+n0..).
// Waves wc<2 hold gate, wc>=2 up; SwiGLU combined through LDS epilogue.
// ---------------------------------------------------------------------------
__global__ __launch_bounds__(512, 2) void gemm1_8p_kernel(
    const bf16_t* __restrict__ X, const bf16_t* __restrict__ Wc,
    bf16_t* __restrict__ X2) {
    __shared__ __align__(16) bf16_t smem[65536];  // 128 KiB
    const int t = threadIdx.x;
    const int lane = t & 63, wid = t >> 6;
    const int wr = wid >> 2, wc = wid & 3;
    const int ln15 = lane & 15, q = lane >> 4;
    const int n0 = blockIdx.x * 128;
    const int m0 = blockIdx.y * 256;

    const int sw = ln15 & 7;
    const int offA0 = (wr * 128 + ln15) * 64 + ((q ^ sw) << 3);
    const int offA1 = (wr * 128 + ln15) * 64 + (((q + 4) ^ sw) << 3);
    const int offB0 = (wc * 64 + ln15) * 64 + ((q ^ sw) << 3);
    const int offB1 = (wc * 64 + ln15) * 64 + (((q + 4) ^ sw) << 3);

    const int rr = t >> 3;
    const int lch = (t & 7) ^ (rr & 7);
    const bf16_t* gA = X + (size_t)(m0 + rr) * 2112 + lch * 8;
    const bf16_t* gB0 = Wc + (size_t)(n0 + rr) * 2112 + lch * 8;          // gate
    const bf16_t* gB2 = Wc + (size_t)(4096 + n0 + rr) * 2112 + lch * 8;   // up

    f32x4 acc[8][4];
    const f32x4 z = {0.f, 0.f, 0.f, 0.f};
#pragma unroll
    for (int i = 0; i < 8; ++i)
#pragma unroll
        for (int j = 0; j < 4; ++j) acc[i][j] = z;

    gemm8p_core<2112, 2112, 33>(gA, gB0, gB2, smem, t, offA0, offA1, offB0,
                                offB1, acc);

    // Epilogue: up waves park acc in LDS (256x128 f32, bank-swizzled), gate
    // waves read the matching up value and apply SwiGLU.
    __syncthreads();
    float* fs = (float*)smem;
    if (wc >= 2) {
#pragma unroll
        for (int mi = 0; mi < 8; ++mi)
#pragma unroll
            for (int nj = 0; nj < 4; ++nj)
#pragma unroll
                for (int rg = 0; rg < 4; ++rg) {
                    int row = wr * 128 + mi * 16 + q * 4 + rg;
                    int col = (wc - 2) * 64 + nj * 16 + ln15;
                    fs[row * 128 + eswz(row, col)] = acc[mi][nj][rg];
                }
    }
    __syncthreads();
    if (wc < 2) {
#pragma unroll
        for (int mi = 0; mi < 8; ++mi)
#pragma unroll
            for (int nj = 0; nj < 4; ++nj)
#pragma unroll
                for (int rg = 0; rg < 4; ++rg) {
                    int row = wr * 128 + mi * 16 + q * 4 + rg;
                    int col = wc * 64 + nj * 16 + ln15;
                    float gv = acc[mi][nj][rg];
                    float uv = fs[row * 128 + eswz(row, col)];
                    float h = uv * gv / (1.f + __expf(-gv));  // up * silu(gate)
                    X2[(size_t)(m0 + row) * 4160 + (n0 + col)] = (bf16_t)h;
                }
    }
}

// ---------------------------------------------------------------------------
// GEMM2: out = X2[8192x4160] @ Wdc[2048x4160]^T, fp32 out.
// grid (8, 32) = 256 blocks = exactly one round at 1 block/CU.
// ---------------------------------------------------------------------------
__global__ __launch_bounds__(512, 2) void gemm2_8p_kernel(
    const bf16_t* __restrict__ X2, const bf16_t* __restrict__ Wdc,
    float* __restrict__ out) {
    __shared__ __align__(16) bf16_t smem[65536];  // 128 KiB
    const int t = threadIdx.x;
    const int lane = t & 63, wid = t >> 6;
    const int wr = wid >> 2, wc = wid & 3;
    const int ln15 = lane & 15, q = lane >> 4;
    const int n0 = blockIdx.x * 256;
    const int m0 = blockIdx.y * 256;

    const int sw = ln15 & 7;
    const int offA0 = (wr * 128 + ln15) * 64 + ((q ^ sw) << 3);
    const int offA1 = (wr * 128 + ln15) * 64 + (((q + 4) ^ sw) << 3);
    const int offB0 = (wc * 64 + ln15) * 64 + ((q ^ sw) << 3);
    const int offB1 = (wc * 64 + ln15) * 64 + (((q + 4) ^ sw) << 3);

    const int rr = t >> 3;
    const int lch = (t & 7) ^ (rr & 7);
    const bf16_t* gA = X2 + (size_t)(m0 + rr) * 4160 + lch * 8;
    const bf16_t* gB0 = Wdc + (size_t)(n0 + rr) * 4160 + lch * 8;
    const bf16_t* gB2 = Wdc + (size_t)(n0 + 128 + rr) * 4160 + lch * 8;

    f32x4 acc[8][4];
    const f32x4 z = {0.f, 0.f, 0.f, 0.f};
#pragma unroll
    for (int i = 0; i < 8; ++i)
#pragma unroll
        for (int j = 0; j < 4; ++j) acc[i][j] = z;

    gemm8p_core<4160, 4160, 65>(gA, gB0, gB2, smem, t, offA0, offA1, offB0,
                                offB1, acc);

#pragma unroll
    for (int mi = 0; mi < 8; ++mi)
#pragma unroll
        for (int nj = 0; nj < 4; ++nj)
#pragma unroll
            for (int rg = 0; rg < 4; ++rg) {
                int row = wr * 128 + mi * 16 + q * 4 + rg;
                int col = wc * 64 + nj * 16 + ln15;
                out[(size_t)(m0 + row) * 2048 + (n0 + col)] = acc[mi][nj][rg];
            }
}

// ---------------------------------------------------------------------------
// Workspace layout (bytes):
//   X1   @ 0         : 8192 x 2112 bf16   [x | 0.25*x@A_gu^T]
//   W1   @ 34603008  : 8192 x 2112 bf16   [W_gu | B_gu]
//   X2   @ 69206016  : 8192 x 4160 bf16   [h | 0.25*h@A_d^T]
//   W2   @ 137363456 : 2048 x 4160 bf16   [W_d | B_d]
//   Abf  @ 154402816 : 64 x 2048 bf16
//   Adbf @ 154664960 : 64 x 4096 bf16
// ---------------------------------------------------------------------------
extern "C" void kernel_launch(void* const* d_in, const int* in_sizes, int n_in,
                              void* d_out, int out_size, void* d_ws, size_t ws_size,
                              hipStream_t stream) {
    const float* x = (const float*)d_in[0];
    const float* Wgu = (const float*)d_in[1];
    const float* Agu = (const float*)d_in[2];
    const float* Bgu = (const float*)d_in[3];
    const float* Wd = (const float*)d_in[4];
    const float* Ad = (const float*)d_in[5];
    const float* Bd = (const float*)d_in[6];
    float* out = (float*)d_out;

    char* ws = (char*)d_ws;
    bf16_t* X1 = (bf16_t*)(ws);
    bf16_t* W1 = (bf16_t*)(ws + 34603008);
    bf16_t* X2 = (bf16_t*)(ws + 69206016);
    bf16_t* W2 = (bf16_t*)(ws + 137363456);
    bf16_t* Abf = (bf16_t*)(ws + 154402816);
    bf16_t* Adbf = (bf16_t*)(ws + 154664960);

    // all fp32 -> bf16 conversions, single launch
    cvt_all_kernel<<<41984, 256, 0, stream>>>(x, Wgu, Bgu, Wd, Bd, Agu, Ad,
                                              X1, W1, W2, Abf, Adbf);

    // t1 = 0.25 * x @ A_gu^T  -> X1 cols [2048,2112)
    lora_kernel<<<128, 256, 0, stream>>>(X1, 2112, Abf, 2048, X1, 2112, 2048);
    // fused gate_up GEMM + SwiGLU -> X2 cols [0,4096)
    gemm1_8p_kernel<<<dim3(32, 32), 512, 0, stream>>>(X1, W1, X2);
    // t2 = 0.25 * h @ A_d^T -> X2 cols [4096,4160)
    lora_kernel<<<128, 256, 0, stream>>>(X2, 4160, Adbf, 4096, X2, 4160, 4096);
    // out = X2 @ [W_d|B_d]^T
    gemm2_8p_kernel<<<dim3(8, 32), 512, 0, stream>>>(X2, W2, out);
}

// Round 3
// 632.747 us; speedup vs baseline: 1.0475x; 1.0475x over previous
//
#include <hip/hip_runtime.h>
#include <stdint.h>

typedef __bf16 bf16_t;
typedef __bf16 bf16x8 __attribute__((ext_vector_type(8)));
typedef __bf16 bf16x4 __attribute__((ext_vector_type(4)));
typedef float f32x4 __attribute__((ext_vector_type(4)));

// Async global->LDS, 16B per lane (wave-uniform base + lane*16).
#define GLOAD16(gp, lp)                                                        \
    __builtin_amdgcn_global_load_lds(                                          \
        (const __attribute__((address_space(1))) void*)(gp),                   \
        (__attribute__((address_space(3))) void*)(lp), 16, 0, 0)

#define MFMA16(a, b, c) __builtin_amdgcn_mfma_f32_16x16x32_bf16(a, b, c, 0, 0, 0)

#define SB() __builtin_amdgcn_sched_barrier(0)
#define BAR() asm volatile("s_barrier" ::: "memory")
#define LGKM0() asm volatile("s_waitcnt lgkmcnt(0)" ::: "memory")
#define VMW(n) asm volatile("s_waitcnt vmcnt(" #n ")" ::: "memory")

// Phase framing for the gemm2 4-phase core (round-1 proven): barrier |
// lgkm(0) | sched_barrier | setprio(1) | MFMA | setprio(0) | barrier.
#define PH_PRE()                                                               \
    do {                                                                       \
        SB();                                                                  \
        BAR();                                                                 \
        LGKM0();                                                               \
        SB();                                                                  \
        __builtin_amdgcn_s_setprio(1);                                         \
    } while (0)
#define PH_POST()                                                              \
    do {                                                                       \
        __builtin_amdgcn_s_setprio(0);                                         \
        SB();                                                                  \
        BAR();                                                                 \
    } while (0)

// BK=64 LDS tiles: row = 64 bf16 = 128 B = 32 banks; chunk c of row r lives
// in slot c ^ (r&7) (pre-swizzled global source, linear LDS dest). Readers
// XOR the same way -> 2-way (free) on ds_read_b128.

// ---------------------------------------------------------------------------
// All fp32 -> bf16 conversions in ONE launch (7 segments).
// ---------------------------------------------------------------------------
__global__ __launch_bounds__(256) void cvt_all_kernel(
    const float* __restrict__ x, const float* __restrict__ Wgu,
    const float* __restrict__ Bgu, const float* __restrict__ Wd,
    const float* __restrict__ Bd, const float* __restrict__ Agu,
    const float* __restrict__ Ad, bf16_t* __restrict__ X1,
    bf16_t* __restrict__ W1, bf16_t* __restrict__ W2,
    bf16_t* __restrict__ Abf, bf16_t* __restrict__ Adbf) {
    int b = blockIdx.x;
    const float* src;
    bf16_t* dst;
    int cshift, cmask, ldd, coff, lb;
    if (b < 16384) {
        src = x; dst = X1; cshift = 11; cmask = 2047; ldd = 2112; coff = 0; lb = b;
    } else if (b < 32768) {
        src = Wgu; dst = W1; cshift = 11; cmask = 2047; ldd = 2112; coff = 0; lb = b - 16384;
    } else if (b < 33280) {
        src = Bgu; dst = W1; cshift = 6; cmask = 63; ldd = 2112; coff = 2048; lb = b - 32768;
    } else if (b < 41472) {
        src = Wd; dst = W2; cshift = 12; cmask = 4095; ldd = 4160; coff = 0; lb = b - 33280;
    } else if (b < 41600) {
        src = Bd; dst = W2; cshift = 6; cmask = 63; ldd = 4160; coff = 4096; lb = b - 41472;
    } else if (b < 41728) {
        src = Agu; dst = Abf; cshift = 11; cmask = 2047; ldd = 2048; coff = 0; lb = b - 41600;
    } else {
        src = Ad; dst = Adbf; cshift = 12; cmask = 4095; ldd = 4096; coff = 0; lb = b - 41728;
    }
    int idx = (lb * 256 + threadIdx.x) << 2;
    int r = idx >> cshift;
    int c = idx & cmask;
    float4 v = *(const float4*)(src + idx);
    bf16x4 o = {(bf16_t)v.x, (bf16_t)v.y, (bf16_t)v.z, (bf16_t)v.w};
    *(bf16x4*)(dst + (size_t)r * ldd + coff + c) = o;
}

// ---------------------------------------------------------------------------
// LoRA GEMM: t = 0.25 * (A[M x K] @ Bw[64 x K]^T) -> dst cols [coff,coff+64).
// ---------------------------------------------------------------------------
__global__ __launch_bounds__(256) void lora_kernel(const bf16_t* __restrict__ A,
                                                   int lda,
                                                   const bf16_t* __restrict__ Bw,
                                                   int K, bf16_t* __restrict__ dst,
                                                   int ldd, int coff) {
    __shared__ __align__(16) bf16_t As[64 * 64];
    __shared__ __align__(16) bf16_t Bs[64 * 64];
    const int t = threadIdx.x;
    const int m0 = blockIdx.x * 64;
    const int lane = t & 63, w = t >> 6;
    const int ln15 = lane & 15, q = lane >> 4;

    const int lrow = t >> 3;
    const int lchunk = (t & 7) ^ (lrow & 7);
    const bf16_t* gaL = A + (size_t)(m0 + lrow) * lda + lchunk * 8;
    const bf16_t* gbL = Bw + (size_t)lrow * K + lchunk * 8;
    bf16_t* lA = As + t * 8;
    bf16_t* lB = Bs + t * 8;

    const f32x4 z = {0.f, 0.f, 0.f, 0.f};
    f32x4 acc[4];
#pragma unroll
    for (int j = 0; j < 4; ++j) acc[j] = z;

    int aoffs[2], boffs[2][4];
#pragma unroll
    for (int s = 0; s < 2; ++s) {
        int rowa = w * 16 + ln15;
        aoffs[s] = rowa * 64 + (((q + 4 * s) ^ (rowa & 7)) << 3);
#pragma unroll
        for (int j = 0; j < 4; ++j) {
            int rowb = j * 16 + ln15;
            boffs[s][j] = rowb * 64 + (((q + 4 * s) ^ (rowb & 7)) << 3);
        }
    }

    for (int kt = 0; kt < K; kt += 64) {
        GLOAD16(gaL, lA);
        GLOAD16(gaL + (size_t)32 * lda, lA + 32 * 64);
        GLOAD16(gbL, lB);
        GLOAD16(gbL + (size_t)32 * K, lB + 32 * 64);
        __syncthreads();
#pragma unroll
        for (int s = 0; s < 2; ++s) {
            bf16x8 av = *(const bf16x8*)(As + aoffs[s]);
#pragma unroll
            for (int j = 0; j < 4; ++j) {
                bf16x8 bv = *(const bf16x8*)(Bs + boffs[s][j]);
                acc[j] = MFMA16(av, bv, acc[j]);
            }
        }
        __syncthreads();
        gaL += 64;
        gbL += 64;
    }

#pragma unroll
    for (int j = 0; j < 4; ++j)
#pragma unroll
        for (int rg = 0; rg < 4; ++rg) {
            int m = m0 + w * 16 + q * 4 + rg;
            dst[(size_t)m * ldd + coff + j * 16 + ln15] = (bf16_t)(acc[j][rg] * 0.25f);
        }
}

// ---------------------------------------------------------------------------
// GEMM1 fused (ROUND-0 version, best measured 247 us): gate_up =
// X1[8192 x 2112] @ Wc^T + SwiGLU. Block: 128 rows x (64 gate + 64 up);
// 33 K-iters, 32 MFMA/wave/iter. LDS 32 KB -> 4 blocks/CU. Balanced
// LDS-read (~113us) vs MFMA (~114us); cross-block TLP gives the overlap.
// ---------------------------------------------------------------------------
__global__ __launch_bounds__(256, 4) void gemm1_kernel(const bf16_t* __restrict__ X,
                                                       const bf16_t* __restrict__ Wc,
                                                       bf16_t* __restrict__ X2) {
    constexpr int LDA = 2112, LDW = 2112, LDX2 = 4160, K = 2112;
    __shared__ __align__(16) bf16_t As[128 * 64];
    __shared__ __align__(16) bf16_t Bs[128 * 64];
    const int t = threadIdx.x;
    const int n0 = blockIdx.x * 64;
    const int m0 = blockIdx.y * 128;
    const int lane = t & 63, w = t >> 6, wr = w >> 1, wc = w & 1;
    const int ln15 = lane & 15, q = lane >> 4;

    const int lrow = t >> 3;
    const int lchunk = (t & 7) ^ (lrow & 7);
    const bf16_t* gaL = X + (size_t)(m0 + lrow) * LDA + lchunk * 8;
    const bf16_t* gbgL = Wc + (size_t)(n0 + lrow) * LDW + lchunk * 8;          // gate
    const bf16_t* gbuL = Wc + (size_t)(4096 + n0 + lrow) * LDW + lchunk * 8;   // up
    bf16_t* lA = As + t * 8;
    bf16_t* lB = Bs + t * 8;

    const f32x4 z = {0.f, 0.f, 0.f, 0.f};
    f32x4 accg[4][2], accu[4][2];
#pragma unroll
    for (int i = 0; i < 4; ++i)
#pragma unroll
        for (int j = 0; j < 2; ++j) {
            accg[i][j] = z;
            accu[i][j] = z;
        }

    int aoffs[2][4], bgoffs[2][2];
#pragma unroll
    for (int s = 0; s < 2; ++s) {
#pragma unroll
        for (int i = 0; i < 4; ++i) {
            int row = wr * 64 + i * 16 + ln15;
            aoffs[s][i] = row * 64 + (((q + 4 * s) ^ (row & 7)) << 3);
        }
#pragma unroll
        for (int j = 0; j < 2; ++j) {
            int row = wc * 32 + j * 16 + ln15;
            bgoffs[s][j] = row * 64 + (((q + 4 * s) ^ (row & 7)) << 3);
        }
    }

    for (int kt = 0; kt < K; kt += 64) {
        GLOAD16(gaL, lA);
        GLOAD16(gaL + (size_t)32 * LDA, lA + 32 * 64);
        GLOAD16(gaL + (size_t)64 * LDA, lA + 64 * 64);
        GLOAD16(gaL + (size_t)96 * LDA, lA + 96 * 64);
        GLOAD16(gbgL, lB);
        GLOAD16(gbgL + (size_t)32 * LDW, lB + 32 * 64);
        GLOAD16(gbuL, lB + 64 * 64);
        GLOAD16(gbuL + (size_t)32 * LDW, lB + 96 * 64);
        __syncthreads();
#pragma unroll
        for (int s = 0; s < 2; ++s) {
            bf16x8 av[4], bg[2], bu[2];
#pragma unroll
            for (int i = 0; i < 4; ++i) av[i] = *(const bf16x8*)(As + aoffs[s][i]);
#pragma unroll
            for (int j = 0; j < 2; ++j) {
                bg[j] = *(const bf16x8*)(Bs + bgoffs[s][j]);
                bu[j] = *(const bf16x8*)(Bs + bgoffs[s][j] + 64 * 64);  // (row+64)&7 == row&7
            }
#pragma unroll
            for (int i = 0; i < 4; ++i)
#pragma unroll
                for (int j = 0; j < 2; ++j) {
                    accg[i][j] = MFMA16(av[i], bg[j], accg[i][j]);
                    accu[i][j] = MFMA16(av[i], bu[j], accu[i][j]);
                }
        }
        __syncthreads();
        gaL += 64;
        gbgL += 64;
        gbuL += 64;
    }

#pragma unroll
    for (int i = 0; i < 4; ++i)
#pragma unroll
        for (int j = 0; j < 2; ++j)
#pragma unroll
            for (int rg = 0; rg < 4; ++rg) {
                int m = m0 + wr * 64 + i * 16 + q * 4 + rg;
                int d = n0 + wc * 32 + j * 16 + ln15;
                float g = accg[i][j][rg];
                float u = accu[i][j][rg];
                float h = u * g / (1.f + __expf(-g));  // up * silu(gate)
                X2[(size_t)m * LDX2 + d] = (bf16_t)h;
            }
}

// ---------------------------------------------------------------------------
// GEMM2, 256x256 4-phase core (ROUND-1 proven, ~ -50us vs 128^2 2-barrier):
// out = X2[8192 x 4160] @ Wdc[2048 x 4160]^T, fp32 out.
// 512 thr = 8 waves (2M x 4N); per-wave 128x64 out. LDS 128 KiB dbuf.
// Per K-tile g, 4 phases (quadrants (0,0),(0,1),(1,1),(1,0)):
//   p1: read a0(8)+b0(4); stage A1(g+1)->other buf
//   p2: read b1(4);       stage A0(g+2)->this buf
//   p3: read a1(8);       stage Blo(g+2)
//   p4: (no reads);       stage Bhi(g+2); vmcnt(6) -> tile g+1 resident
// grid (8, 32) = 256 blocks = exactly one round at 1 block/CU.
// ---------------------------------------------------------------------------
__global__ __launch_bounds__(512, 2) void gemm2_8p_kernel(
    const bf16_t* __restrict__ X2, const bf16_t* __restrict__ Wdc,
    float* __restrict__ out) {
    constexpr int LDA_ = 4160, LDB_ = 4160, NT_ = 65;
    __shared__ __align__(16) bf16_t smem[65536];  // 128 KiB
    const int t = threadIdx.x;
    const int lane = t & 63, wid = t >> 6;
    const int wr = wid >> 2, wc = wid & 3;
    const int ln15 = lane & 15, q = lane >> 4;
    const int n0 = blockIdx.x * 256;
    const int m0 = blockIdx.y * 256;

    const int sw = ln15 & 7;
    const int offA0 = (wr * 128 + ln15) * 64 + ((q ^ sw) << 3);
    const int offA1 = (wr * 128 + ln15) * 64 + (((q + 4) ^ sw) << 3);
    const int offB0 = (wc * 64 + ln15) * 64 + ((q ^ sw) << 3);
    const int offB1 = (wc * 64 + ln15) * 64 + (((q + 4) ^ sw) << 3);

    const int rr = t >> 3;
    const int lch = (t & 7) ^ (rr & 7);
    const bf16_t* gA = X2 + (size_t)(m0 + rr) * LDA_ + lch * 8;
    const bf16_t* gB0 = Wdc + (size_t)(n0 + rr) * LDB_ + lch * 8;
    const bf16_t* gB2 = Wdc + (size_t)(n0 + 128 + rr) * LDB_ + lch * 8;

    f32x4 acc[8][4];
    const f32x4 z = {0.f, 0.f, 0.f, 0.f};
#pragma unroll
    for (int i = 0; i < 8; ++i)
#pragma unroll
        for (int j = 0; j < 4; ++j) acc[i][j] = z;

    auto stgA0 = [&](int kt, bf16_t* d) {  // rows {0-63,128-191}
        GLOAD16(gA + kt, d + t * 8);
        GLOAD16(gA + (size_t)128 * LDA_ + kt, d + 128 * 64 + t * 8);
    };
    auto stgA1 = [&](int kt, bf16_t* d) {  // rows {64-127,192-255}
        GLOAD16(gA + (size_t)64 * LDA_ + kt, d + 64 * 64 + t * 8);
        GLOAD16(gA + (size_t)192 * LDA_ + kt, d + 192 * 64 + t * 8);
    };
    auto stgBlo = [&](int kt, bf16_t* d) {  // B rows 0-127
        GLOAD16(gB0 + kt, d + t * 8);
        GLOAD16(gB0 + (size_t)64 * LDB_ + kt, d + 64 * 64 + t * 8);
    };
    auto stgBhi = [&](int kt, bf16_t* d) {  // B rows 128-255
        GLOAD16(gB2 + kt, d + 128 * 64 + t * 8);
        GLOAD16(gB2 + (size_t)64 * LDB_ + kt, d + 192 * 64 + t * 8);
    };

    // prologue: tile0 full (8 loads) -> buf0, tile1 minus A1 (6) -> buf1.
    stgA0(0, smem);
    stgA1(0, smem);
    stgBlo(0, smem + 32768);
    stgBhi(0, smem + 32768);
    stgA0(64, smem + 16384);
    stgBlo(64, smem + 49152);
    stgBhi(64, smem + 49152);
    VMW(6);  // tile0 resident (tile1's 6 stay in flight)
    BAR();

    bf16x8 av[4][2], b0[2][2], b1[2][2];
    for (int g = 0; g < NT_; ++g) {
        const int bs = (g & 1) << 14;
        bf16_t* const Asc = smem + bs;
        bf16_t* const Bsc = smem + 32768 + bs;
        bf16_t* const Asn = smem + (bs ^ 16384);
        const int k1 = (g + 1) << 6, k2 = (g + 2) << 6;

        // ---- phase 1 (qi=0, qj=0): read a0 + b0; stage A1(g+1) ----
#pragma unroll
        for (int m = 0; m < 4; ++m) {
            av[m][0] = *(const bf16x8*)(Asc + offA0 + m * 1024);
            av[m][1] = *(const bf16x8*)(Asc + offA1 + m * 1024);
        }
#pragma unroll
        for (int n = 0; n < 2; ++n) {
            b0[n][0] = *(const bf16x8*)(Bsc + offB0 + n * 1024);
            b0[n][1] = *(const bf16x8*)(Bsc + offB1 + n * 1024);
        }
        if (g + 1 < NT_) stgA1(k1, Asn);
        PH_PRE();
#pragma unroll
        for (int m = 0; m < 4; ++m)
#pragma unroll
            for (int n = 0; n < 2; ++n) {
                acc[m][n] = MFMA16(av[m][0], b0[n][0], acc[m][n]);
                acc[m][n] = MFMA16(av[m][1], b0[n][1], acc[m][n]);
            }
        PH_POST();

        // ---- phase 2 (qi=0, qj=1): read b1; stage A0(g+2) ----
#pragma unroll
        for (int n = 0; n < 2; ++n) {
            b1[n][0] = *(const bf16x8*)(Bsc + offB0 + (2 + n) * 1024);
            b1[n][1] = *(const bf16x8*)(Bsc + offB1 + (2 + n) * 1024);
        }
        if (g + 2 < NT_) stgA0(k2, Asc);
        PH_PRE();
#pragma unroll
        for (int m = 0; m < 4; ++m)
#pragma unroll
            for (int n = 0; n < 2; ++n) {
                acc[m][2 + n] = MFMA16(av[m][0], b1[n][0], acc[m][2 + n]);
                acc[m][2 + n] = MFMA16(av[m][1], b1[n][1], acc[m][2 + n]);
            }
        PH_POST();

        // ---- phase 3 (qi=1, qj=1): read a1; stage Blo(g+2) ----
#pragma unroll
        for (int m = 0; m < 4; ++m) {
            av[m][0] = *(const bf16x8*)(Asc + offA0 + (4 + m) * 1024);
            av[m][1] = *(const bf16x8*)(Asc + offA1 + (4 + m) * 1024);
        }
        if (g + 2 < NT_) stgBlo(k2, Bsc);
        PH_PRE();
#pragma unroll
        for (int m = 0; m < 4; ++m)
#pragma unroll
            for (int n = 0; n < 2; ++n) {
                acc[4 + m][2 + n] = MFMA16(av[m][0], b1[n][0], acc[4 + m][2 + n]);
                acc[4 + m][2 + n] = MFMA16(av[m][1], b1[n][1], acc[4 + m][2 + n]);
            }
        PH_POST();

        // ---- phase 4 (qi=1, qj=0): stage Bhi(g+2); vmcnt gate ----
        if (g + 2 < NT_) stgBhi(k2, Bsc);
        PH_PRE();
#pragma unroll
        for (int m = 0; m < 4; ++m)
#pragma unroll
            for (int n = 0; n < 2; ++n) {
                acc[4 + m][n] = MFMA16(av[m][0], b0[n][0], acc[4 + m][n]);
                acc[4 + m][n] = MFMA16(av[m][1], b0[n][1], acc[4 + m][n]);
            }
        __builtin_amdgcn_s_setprio(0);
        SB();
        if (g + 2 < NT_)
            VMW(6);
        else
            VMW(0);
        BAR();
    }

#pragma unroll
    for (int mi = 0; mi < 8; ++mi)
#pragma unroll
        for (int nj = 0; nj < 4; ++nj)
#pragma unroll
            for (int rg = 0; rg < 4; ++rg) {
                int row = wr * 128 + mi * 16 + q * 4 + rg;
                int col = wc * 64 + nj * 16 + ln15;
                out[(size_t)(m0 + row) * 2048 + (n0 + col)] = acc[mi][nj][rg];
            }
}

// ---------------------------------------------------------------------------
// Workspace layout (bytes):
//   X1   @ 0         : 8192 x 2112 bf16   [x | 0.25*x@A_gu^T]
//   W1   @ 34603008  : 8192 x 2112 bf16   [W_gu | B_gu]
//   X2   @ 69206016  : 8192 x 4160 bf16   [h | 0.25*h@A_d^T]
//   W2   @ 137363456 : 2048 x 4160 bf16   [W_d | B_d]
//   Abf  @ 154402816 : 64 x 2048 bf16
//   Adbf @ 154664960 : 64 x 4096 bf16
// ---------------------------------------------------------------------------
extern "C" void kernel_launch(void* const* d_in, const int* in_sizes, int n_in,
                              void* d_out, int out_size, void* d_ws, size_t ws_size,
                              hipStream_t stream) {
    const float* x = (const float*)d_in[0];
    const float* Wgu = (const float*)d_in[1];
    const float* Agu = (const float*)d_in[2];
    const float* Bgu = (const float*)d_in[3];
    const float* Wd = (const float*)d_in[4];
    const float* Ad = (const float*)d_in[5];
    const float* Bd = (const float*)d_in[6];
    float* out = (float*)d_out;

    char* ws = (char*)d_ws;
    bf16_t* X1 = (bf16_t*)(ws);
    bf16_t* W1 = (bf16_t*)(ws + 34603008);
    bf16_t* X2 = (bf16_t*)(ws + 69206016);
    bf16_t* W2 = (bf16_t*)(ws + 137363456);
    bf16_t* Abf = (bf16_t*)(ws + 154402816);
    bf16_t* Adbf = (bf16_t*)(ws + 154664960);

    // all fp32 -> bf16 conversions, single launch
    cvt_all_kernel<<<41984, 256, 0, stream>>>(x, Wgu, Bgu, Wd, Bd, Agu, Ad,
                                              X1, W1, W2, Abf, Adbf);

    // t1 = 0.25 * x @ A_gu^T  -> X1 cols [2048,2112)
    lora_kernel<<<128, 256, 0, stream>>>(X1, 2112, Abf, 2048, X1, 2112, 2048);
    // fused gate_up GEMM + SwiGLU -> X2 cols [0,4096)   (round-0 kernel)
    gemm1_kernel<<<dim3(64, 64), 256, 0, stream>>>(X1, W1, X2);
    // t2 = 0.25 * h @ A_d^T -> X2 cols [4096,4160)
    lora_kernel<<<128, 256, 0, stream>>>(X2, 4160, Adbf, 4096, X2, 4160, 4096);
    // out = X2 @ [W_d|B_d]^T   (round-1 256^2 4-phase core)
    gemm2_8p_kernel<<<dim3(8, 32), 512, 0, stream>>>(X2, W2, out);
}

// Round 4
// 611.999 us; speedup vs baseline: 1.0830x; 1.0339x over previous
//
#include <hip/hip_runtime.h>
#include <stdint.h>

typedef __bf16 bf16_t;
typedef __bf16 bf16x8 __attribute__((ext_vector_type(8)));
typedef __bf16 bf16x4 __attribute__((ext_vector_type(4)));
typedef float f32x4 __attribute__((ext_vector_type(4)));

// Async global->LDS, 16B per lane (wave-uniform base + lane*16).
#define GLOAD16(gp, lp)                                                        \
    __builtin_amdgcn_global_load_lds(                                          \
        (const __attribute__((address_space(1))) void*)(gp),                   \
        (__attribute__((address_space(3))) void*)(lp), 16, 0, 0)

#define MFMA16(a, b, c) __builtin_amdgcn_mfma_f32_16x16x32_bf16(a, b, c, 0, 0, 0)

#define SB() __builtin_amdgcn_sched_barrier(0)
#define BAR() asm volatile("s_barrier" ::: "memory")
#define LGKM0() asm volatile("s_waitcnt lgkmcnt(0)" ::: "memory")
#define VMW(n) asm volatile("s_waitcnt vmcnt(" #n ")" ::: "memory")

// Phase framing for the gemm2 4-phase core: barrier | lgkm(0) |
// sched_barrier | setprio(1) | MFMA | setprio(0) | barrier.
#define PH_PRE()                                                               \
    do {                                                                       \
        SB();                                                                  \
        BAR();                                                                 \
        LGKM0();                                                               \
        SB();                                                                  \
        __builtin_amdgcn_s_setprio(1);                                         \
    } while (0)
#define PH_POST()                                                              \
    do {                                                                       \
        __builtin_amdgcn_s_setprio(0);                                         \
        SB();                                                                  \
        BAR();                                                                 \
    } while (0)

// BK=64 LDS tiles: row = 64 bf16 = 128 B = 32 banks; chunk c of row r lives
// in slot c ^ (r&7) (pre-swizzled global source, linear LDS dest). Readers
// XOR the same way -> 2-way (free) on ds_read_b128.

// ---------------------------------------------------------------------------
// All fp32 -> bf16 conversions in ONE launch (7 segments).
// ---------------------------------------------------------------------------
__global__ __launch_bounds__(256) void cvt_all_kernel(
    const float* __restrict__ x, const float* __restrict__ Wgu,
    const float* __restrict__ Bgu, const float* __restrict__ Wd,
    const float* __restrict__ Bd, const float* __restrict__ Agu,
    const float* __restrict__ Ad, bf16_t* __restrict__ X1,
    bf16_t* __restrict__ W1, bf16_t* __restrict__ W2,
    bf16_t* __restrict__ Abf, bf16_t* __restrict__ Adbf) {
    int b = blockIdx.x;
    const float* src;
    bf16_t* dst;
    int cshift, cmask, ldd, coff, lb;
    if (b < 16384) {
        src = x; dst = X1; cshift = 11; cmask = 2047; ldd = 2112; coff = 0; lb = b;
    } else if (b < 32768) {
        src = Wgu; dst = W1; cshift = 11; cmask = 2047; ldd = 2112; coff = 0; lb = b - 16384;
    } else if (b < 33280) {
        src = Bgu; dst = W1; cshift = 6; cmask = 63; ldd = 2112; coff = 2048; lb = b - 32768;
    } else if (b < 41472) {
        src = Wd; dst = W2; cshift = 12; cmask = 4095; ldd = 4160; coff = 0; lb = b - 33280;
    } else if (b < 41600) {
        src = Bd; dst = W2; cshift = 6; cmask = 63; ldd = 4160; coff = 4096; lb = b - 41472;
    } else if (b < 41728) {
        src = Agu; dst = Abf; cshift = 11; cmask = 2047; ldd = 2048; coff = 0; lb = b - 41600;
    } else {
        src = Ad; dst = Adbf; cshift = 12; cmask = 4095; ldd = 4096; coff = 0; lb = b - 41728;
    }
    int idx = (lb * 256 + threadIdx.x) << 2;
    int r = idx >> cshift;
    int c = idx & cmask;
    float4 v = *(const float4*)(src + idx);
    bf16x4 o = {(bf16_t)v.x, (bf16_t)v.y, (bf16_t)v.z, (bf16_t)v.w};
    *(bf16x4*)(dst + (size_t)r * ldd + coff + c) = o;
}

// ---------------------------------------------------------------------------
// LoRA GEMM: t = 0.25 * (A[M x K] @ Bw[64 x K]^T) -> dst cols [coff,coff+64).
// ---------------------------------------------------------------------------
__global__ __launch_bounds__(256) void lora_kernel(const bf16_t* __restrict__ A,
                                                   int lda,
                                                   const bf16_t* __restrict__ Bw,
                                                   int K, bf16_t* __restrict__ dst,
                                                   int ldd, int coff) {
    __shared__ __align__(16) bf16_t As[64 * 64];
    __shared__ __align__(16) bf16_t Bs[64 * 64];
    const int t = threadIdx.x;
    const int m0 = blockIdx.x * 64;
    const int lane = t & 63, w = t >> 6;
    const int ln15 = lane & 15, q = lane >> 4;

    const int lrow = t >> 3;
    const int lchunk = (t & 7) ^ (lrow & 7);
    const bf16_t* gaL = A + (size_t)(m0 + lrow) * lda + lchunk * 8;
    const bf16_t* gbL = Bw + (size_t)lrow * K + lchunk * 8;
    bf16_t* lA = As + t * 8;
    bf16_t* lB = Bs + t * 8;

    const f32x4 z = {0.f, 0.f, 0.f, 0.f};
    f32x4 acc[4];
#pragma unroll
    for (int j = 0; j < 4; ++j) acc[j] = z;

    int aoffs[2], boffs[2][4];
#pragma unroll
    for (int s = 0; s < 2; ++s) {
        int rowa = w * 16 + ln15;
        aoffs[s] = rowa * 64 + (((q + 4 * s) ^ (rowa & 7)) << 3);
#pragma unroll
        for (int j = 0; j < 4; ++j) {
            int rowb = j * 16 + ln15;
            boffs[s][j] = rowb * 64 + (((q + 4 * s) ^ (rowb & 7)) << 3);
        }
    }

    for (int kt = 0; kt < K; kt += 64) {
        GLOAD16(gaL, lA);
        GLOAD16(gaL + (size_t)32 * lda, lA + 32 * 64);
        GLOAD16(gbL, lB);
        GLOAD16(gbL + (size_t)32 * K, lB + 32 * 64);
        __syncthreads();
#pragma unroll
        for (int s = 0; s < 2; ++s) {
            bf16x8 av = *(const bf16x8*)(As + aoffs[s]);
#pragma unroll
            for (int j = 0; j < 4; ++j) {
                bf16x8 bv = *(const bf16x8*)(Bs + boffs[s][j]);
                acc[j] = MFMA16(av, bv, acc[j]);
            }
        }
        __syncthreads();
        gaL += 64;
        gbL += 64;
    }

#pragma unroll
    for (int j = 0; j < 4; ++j)
#pragma unroll
        for (int rg = 0; rg < 4; ++rg) {
            int m = m0 + w * 16 + q * 4 + rg;
            dst[(size_t)m * ldd + coff + j * 16 + ln15] = (bf16_t)(acc[j][rg] * 0.25f);
        }
}

// ---------------------------------------------------------------------------
// GEMM1 v2 (LDS-BW fix): per-wave tile 128x64 (was 64x64).
// R0 was LDS-read-bound: 16 waves/CU x 16 ds_read_b128/K-tile = 1000 cy LDS
// vs 620 cy MFMA -> 62% ceiling (measured 58%). 128x64/wave: reads/MFMA
// drops 16/32 -> 24/64, ceiling ~81%.
// Block: 256 thr = 4 waves (2M x 2N). Tile M=256, out-cols 64 (gate+up).
// Per wave: acc[8][4] (nj 0-1 gate, 2-3 up) = 128 regs; SwiGLU in-register.
// LDS: A 256x64 + B 128x64 (rows 0-63 gate, 64-127 up) = 48 KB -> 2 blk/CU.
// Same plain 2-barrier loop as R0 (cross-block TLP covers the drain).
// ---------------------------------------------------------------------------
__global__ __launch_bounds__(256, 2) void gemm1_kernel(const bf16_t* __restrict__ X,
                                                       const bf16_t* __restrict__ Wc,
                                                       bf16_t* __restrict__ X2) {
    constexpr int LDA = 2112, LDW = 2112, LDX2 = 4160, K = 2112;
    __shared__ __align__(16) bf16_t As[256 * 64];  // 32 KB
    __shared__ __align__(16) bf16_t Bs[128 * 64];  // 16 KB
    const int t = threadIdx.x;
    const int n0 = blockIdx.x * 64;
    const int m0 = blockIdx.y * 256;
    const int lane = t & 63, w = t >> 6, wr = w >> 1, wc = w & 1;
    const int ln15 = lane & 15, q = lane >> 4;

    const int lrow = t >> 3;
    const int lchunk = (t & 7) ^ (lrow & 7);
    const bf16_t* gaL = X + (size_t)(m0 + lrow) * LDA + lchunk * 8;
    const bf16_t* gbgL = Wc + (size_t)(n0 + lrow) * LDW + lchunk * 8;          // gate
    const bf16_t* gbuL = Wc + (size_t)(4096 + n0 + lrow) * LDW + lchunk * 8;   // up
    bf16_t* lA = As + t * 8;
    bf16_t* lB = Bs + t * 8;

    const f32x4 z = {0.f, 0.f, 0.f, 0.f};
    f32x4 acc[8][4];  // [mi][nj]: nj 0-1 gate, 2-3 up
#pragma unroll
    for (int i = 0; i < 8; ++i)
#pragma unroll
        for (int j = 0; j < 4; ++j) acc[i][j] = z;

    // row&7 == ln15&7 for every fragment (frag strides are multiples of 16),
    // so each s-half needs only one base offset; frag steps are +1024.
    const int sw7 = ln15 & 7;
    const int arow = wr * 128 + ln15;
    const int aoff0 = arow * 64 + ((q ^ sw7) << 3);
    const int aoff1 = arow * 64 + (((q + 4) ^ sw7) << 3);
    const int brow = wc * 32 + ln15;
    const int boff0 = brow * 64 + ((q ^ sw7) << 3);
    const int boff1 = brow * 64 + (((q + 4) ^ sw7) << 3);

    for (int kt = 0; kt < K; kt += 64) {
        GLOAD16(gaL, lA);
        GLOAD16(gaL + (size_t)32 * LDA, lA + 32 * 64);
        GLOAD16(gaL + (size_t)64 * LDA, lA + 64 * 64);
        GLOAD16(gaL + (size_t)96 * LDA, lA + 96 * 64);
        GLOAD16(gaL + (size_t)128 * LDA, lA + 128 * 64);
        GLOAD16(gaL + (size_t)160 * LDA, lA + 160 * 64);
        GLOAD16(gaL + (size_t)192 * LDA, lA + 192 * 64);
        GLOAD16(gaL + (size_t)224 * LDA, lA + 224 * 64);
        GLOAD16(gbgL, lB);
        GLOAD16(gbgL + (size_t)32 * LDW, lB + 32 * 64);
        GLOAD16(gbuL, lB + 64 * 64);
        GLOAD16(gbuL + (size_t)32 * LDW, lB + 96 * 64);
        __syncthreads();
#pragma unroll
        for (int s = 0; s < 2; ++s) {
            const int ao = s ? aoff1 : aoff0;
            const int bo = s ? boff1 : boff0;
            bf16x8 bv[4];
            bv[0] = *(const bf16x8*)(Bs + bo);                  // gate nj=0
            bv[1] = *(const bf16x8*)(Bs + bo + 1024);           // gate nj=1
            bv[2] = *(const bf16x8*)(Bs + bo + 64 * 64);        // up   nj=0
            bv[3] = *(const bf16x8*)(Bs + bo + 64 * 64 + 1024); // up   nj=1
#pragma unroll
            for (int g2 = 0; g2 < 2; ++g2) {
                bf16x8 av[4];
#pragma unroll
                for (int i = 0; i < 4; ++i)
                    av[i] = *(const bf16x8*)(As + ao + (g2 * 4 + i) * 1024);
#pragma unroll
                for (int i = 0; i < 4; ++i)
#pragma unroll
                    for (int j = 0; j < 4; ++j)
                        acc[g2 * 4 + i][j] = MFMA16(av[i], bv[j], acc[g2 * 4 + i][j]);
            }
        }
        __syncthreads();
        gaL += 64;
        gbgL += 64;
        gbuL += 64;
    }

#pragma unroll
    for (int mi = 0; mi < 8; ++mi)
#pragma unroll
        for (int nj = 0; nj < 2; ++nj)
#pragma unroll
            for (int rg = 0; rg < 4; ++rg) {
                int m = m0 + wr * 128 + mi * 16 + q * 4 + rg;
                int d = n0 + wc * 32 + nj * 16 + ln15;
                float g = acc[mi][nj][rg];
                float u = acc[mi][nj + 2][rg];
                float h = u * g / (1.f + __expf(-g));  // up * silu(gate)
                X2[(size_t)m * LDX2 + d] = (bf16_t)h;
            }
}

// ---------------------------------------------------------------------------
// GEMM2, 256x256 4-phase core (unchanged from round 3):
// out = X2[8192 x 4160] @ Wdc[2048 x 4160]^T, fp32 out.
// ---------------------------------------------------------------------------
__global__ __launch_bounds__(512, 2) void gemm2_8p_kernel(
    const bf16_t* __restrict__ X2, const bf16_t* __restrict__ Wdc,
    float* __restrict__ out) {
    constexpr int LDA_ = 4160, LDB_ = 4160, NT_ = 65;
    __shared__ __align__(16) bf16_t smem[65536];  // 128 KiB
    const int t = threadIdx.x;
    const int lane = t & 63, wid = t >> 6;
    const int wr = wid >> 2, wc = wid & 3;
    const int ln15 = lane & 15, q = lane >> 4;
    const int n0 = blockIdx.x * 256;
    const int m0 = blockIdx.y * 256;

    const int sw = ln15 & 7;
    const int offA0 = (wr * 128 + ln15) * 64 + ((q ^ sw) << 3);
    const int offA1 = (wr * 128 + ln15) * 64 + (((q + 4) ^ sw) << 3);
    const int offB0 = (wc * 64 + ln15) * 64 + ((q ^ sw) << 3);
    const int offB1 = (wc * 64 + ln15) * 64 + (((q + 4) ^ sw) << 3);

    const int rr = t >> 3;
    const int lch = (t & 7) ^ (rr & 7);
    const bf16_t* gA = X2 + (size_t)(m0 + rr) * LDA_ + lch * 8;
    const bf16_t* gB0 = Wdc + (size_t)(n0 + rr) * LDB_ + lch * 8;
    const bf16_t* gB2 = Wdc + (size_t)(n0 + 128 + rr) * LDB_ + lch * 8;

    f32x4 acc[8][4];
    const f32x4 z = {0.f, 0.f, 0.f, 0.f};
#pragma unroll
    for (int i = 0; i < 8; ++i)
#pragma unroll
        for (int j = 0; j < 4; ++j) acc[i][j] = z;

    auto stgA0 = [&](int kt, bf16_t* d) {  // rows {0-63,128-191}
        GLOAD16(gA + kt, d + t * 8);
        GLOAD16(gA + (size_t)128 * LDA_ + kt, d + 128 * 64 + t * 8);
    };
    auto stgA1 = [&](int kt, bf16_t* d) {  // rows {64-127,192-255}
        GLOAD16(gA + (size_t)64 * LDA_ + kt, d + 64 * 64 + t * 8);
        GLOAD16(gA + (size_t)192 * LDA_ + kt, d + 192 * 64 + t * 8);
    };
    auto stgBlo = [&](int kt, bf16_t* d) {  // B rows 0-127
        GLOAD16(gB0 + kt, d + t * 8);
        GLOAD16(gB0 + (size_t)64 * LDB_ + kt, d + 64 * 64 + t * 8);
    };
    auto stgBhi = [&](int kt, bf16_t* d) {  // B rows 128-255
        GLOAD16(gB2 + kt, d + 128 * 64 + t * 8);
        GLOAD16(gB2 + (size_t)64 * LDB_ + kt, d + 192 * 64 + t * 8);
    };

    // prologue: tile0 full (8 loads) -> buf0, tile1 minus A1 (6) -> buf1.
    stgA0(0, smem);
    stgA1(0, smem);
    stgBlo(0, smem + 32768);
    stgBhi(0, smem + 32768);
    stgA0(64, smem + 16384);
    stgBlo(64, smem + 49152);
    stgBhi(64, smem + 49152);
    VMW(6);  // tile0 resident (tile1's 6 stay in flight)
    BAR();

    bf16x8 av[4][2], b0[2][2], b1[2][2];
    for (int g = 0; g < NT_; ++g) {
        const int bs = (g & 1) << 14;
        bf16_t* const Asc = smem + bs;
        bf16_t* const Bsc = smem + 32768 + bs;
        bf16_t* const Asn = smem + (bs ^ 16384);
        const int k1 = (g + 1) << 6, k2 = (g + 2) << 6;

        // ---- phase 1 (qi=0, qj=0): read a0 + b0; stage A1(g+1) ----
#pragma unroll
        for (int m = 0; m < 4; ++m) {
            av[m][0] = *(const bf16x8*)(Asc + offA0 + m * 1024);
            av[m][1] = *(const bf16x8*)(Asc + offA1 + m * 1024);
        }
#pragma unroll
        for (int n = 0; n < 2; ++n) {
            b0[n][0] = *(const bf16x8*)(Bsc + offB0 + n * 1024);
            b0[n][1] = *(const bf16x8*)(Bsc + offB1 + n * 1024);
        }
        if (g + 1 < NT_) stgA1(k1, Asn);
        PH_PRE();
#pragma unroll
        for (int m = 0; m < 4; ++m)
#pragma unroll
            for (int n = 0; n < 2; ++n) {
                acc[m][n] = MFMA16(av[m][0], b0[n][0], acc[m][n]);
                acc[m][n] = MFMA16(av[m][1], b0[n][1], acc[m][n]);
            }
        PH_POST();

        // ---- phase 2 (qi=0, qj=1): read b1; stage A0(g+2) ----
#pragma unroll
        for (int n = 0; n < 2; ++n) {
            b1[n][0] = *(const bf16x8*)(Bsc + offB0 + (2 + n) * 1024);
            b1[n][1] = *(const bf16x8*)(Bsc + offB1 + (2 + n) * 1024);
        }
        if (g + 2 < NT_) stgA0(k2, Asc);
        PH_PRE();
#pragma unroll
        for (int m = 0; m < 4; ++m)
#pragma unroll
            for (int n = 0; n < 2; ++n) {
                acc[m][2 + n] = MFMA16(av[m][0], b1[n][0], acc[m][2 + n]);
                acc[m][2 + n] = MFMA16(av[m][1], b1[n][1], acc[m][2 + n]);
            }
        PH_POST();

        // ---- phase 3 (qi=1, qj=1): read a1; stage Blo(g+2) ----
#pragma unroll
        for (int m = 0; m < 4; ++m) {
            av[m][0] = *(const bf16x8*)(Asc + offA0 + (4 + m) * 1024);
            av[m][1] = *(const bf16x8*)(Asc + offA1 + (4 + m) * 1024);
        }
        if (g + 2 < NT_) stgBlo(k2, Bsc);
        PH_PRE();
#pragma unroll
        for (int m = 0; m < 4; ++m)
#pragma unroll
            for (int n = 0; n < 2; ++n) {
                acc[4 + m][2 + n] = MFMA16(av[m][0], b1[n][0], acc[4 + m][2 + n]);
                acc[4 + m][2 + n] = MFMA16(av[m][1], b1[n][1], acc[4 + m][2 + n]);
            }
        PH_POST();

        // ---- phase 4 (qi=1, qj=0): stage Bhi(g+2); vmcnt gate ----
        if (g + 2 < NT_) stgBhi(k2, Bsc);
        PH_PRE();
#pragma unroll
        for (int m = 0; m < 4; ++m)
#pragma unroll
            for (int n = 0; n < 2; ++n) {
                acc[4 + m][n] = MFMA16(av[m][0], b0[n][0], acc[4 + m][n]);
                acc[4 + m][n] = MFMA16(av[m][1], b0[n][1], acc[4 + m][n]);
            }
        __builtin_amdgcn_s_setprio(0);
        SB();
        if (g + 2 < NT_)
            VMW(6);
        else
            VMW(0);
        BAR();
    }

#pragma unroll
    for (int mi = 0; mi < 8; ++mi)
#pragma unroll
        for (int nj = 0; nj < 4; ++nj)
#pragma unroll
            for (int rg = 0; rg < 4; ++rg) {
                int row = wr * 128 + mi * 16 + q * 4 + rg;
                int col = wc * 64 + nj * 16 + ln15;
                out[(size_t)(m0 + row) * 2048 + (n0 + col)] = acc[mi][nj][rg];
            }
}

// ---------------------------------------------------------------------------
// Workspace layout (bytes):
//   X1   @ 0         : 8192 x 2112 bf16   [x | 0.25*x@A_gu^T]
//   W1   @ 34603008  : 8192 x 2112 bf16   [W_gu | B_gu]
//   X2   @ 69206016  : 8192 x 4160 bf16   [h | 0.25*h@A_d^T]
//   W2   @ 137363456 : 2048 x 4160 bf16   [W_d | B_d]
//   Abf  @ 154402816 : 64 x 2048 bf16
//   Adbf @ 154664960 : 64 x 4096 bf16
// ---------------------------------------------------------------------------
extern "C" void kernel_launch(void* const* d_in, const int* in_sizes, int n_in,
                              void* d_out, int out_size, void* d_ws, size_t ws_size,
                              hipStream_t stream) {
    const float* x = (const float*)d_in[0];
    const float* Wgu = (const float*)d_in[1];
    const float* Agu = (const float*)d_in[2];
    const float* Bgu = (const float*)d_in[3];
    const float* Wd = (const float*)d_in[4];
    const float* Ad = (const float*)d_in[5];
    const float* Bd = (const float*)d_in[6];
    float* out = (float*)d_out;

    char* ws = (char*)d_ws;
    bf16_t* X1 = (bf16_t*)(ws);
    bf16_t* W1 = (bf16_t*)(ws + 34603008);
    bf16_t* X2 = (bf16_t*)(ws + 69206016);
    bf16_t* W2 = (bf16_t*)(ws + 137363456);
    bf16_t* Abf = (bf16_t*)(ws + 154402816);
    bf16_t* Adbf = (bf16_t*)(ws + 154664960);

    // all fp32 -> bf16 conversions, single launch
    cvt_all_kernel<<<41984, 256, 0, stream>>>(x, Wgu, Bgu, Wd, Bd, Agu, Ad,
                                              X1, W1, W2, Abf, Adbf);

    // t1 = 0.25 * x @ A_gu^T  -> X1 cols [2048,2112)
    lora_kernel<<<128, 256, 0, stream>>>(X1, 2112, Abf, 2048, X1, 2112, 2048);
    // fused gate_up GEMM + SwiGLU -> X2 cols [0,4096)  (v2: 128x64/wave)
    gemm1_kernel<<<dim3(64, 32), 256, 0, stream>>>(X1, W1, X2);
    // t2 = 0.25 * h @ A_d^T -> X2 cols [4096,4160)
    lora_kernel<<<128, 256, 0, stream>>>(X2, 4160, Adbf, 4096, X2, 4160, 4096);
    // out = X2 @ [W_d|B_d]^T   (256^2 4-phase core)
    gemm2_8p_kernel<<<dim3(8, 32), 512, 0, stream>>>(X2, W2, out);
}